// Round 1
// baseline (2116.469 us; speedup 1.0000x reference)
//
#include <hip/hip_runtime.h>
#include <math.h>

// ---------------- problem constants (fixed by reference file) ----------------
#define N_TOK   2048      // NC * PY * PX
#define DIM     1024
#define HEADS   16
#define HD      64        // head dim
#define NCAMS   2
#define NPER    1024      // tokens per camera (32*32)
#define DPROJ   32        // first half: projective 4x4 groups
#define NF      8         // rope freqs
// image 448x448, patch 32x32 (hard-coded per reference constants)

// ---------------- workspace layout (floats) ----------------
// mats: per camera 48 floats: [0..15]=Aq (=Pinv^T), [16..31]=Ak (=P), [32..47]=Ao (=Pinv)
#define MATS_OFF 0
#define QKV_OFF  256                                   // 2048*3072
#define Q_OFF    (QKV_OFF + N_TOK*3*DIM)               // 16*2048*64 each
#define K_OFF    (Q_OFF + HEADS*N_TOK*HD)
#define V_OFF    (K_OFF + HEADS*N_TOK*HD)
#define O_OFF    (V_OFF + HEADS*N_TOK*HD)
#define OT_OFF   (O_OFF + HEADS*N_TOK*HD)
// total = OT_OFF + 2048*1024 = 16,777,472 floats = 67.1 MB

// ---------------- per-camera matrices ----------------
__global__ void build_mats(const float* __restrict__ ext, const float* __restrict__ Ks,
                           float* __restrict__ mats) {
    int c = threadIdx.x;
    if (c >= NCAMS) return;
    const float sx = 2.0f / 448.0f, sy = 2.0f / 448.0f;
    const float* Kc = Ks + c * 9;
    const float* E  = ext + c * 16;
    float Kn[16];
#pragma unroll
    for (int i = 0; i < 16; i++) Kn[i] = 0.0f;
    Kn[0]  = Kc[0] * sx;            // fx*sx
    Kn[2]  = Kc[2] * sx - 1.0f;     // cx*sx-1
    Kn[5]  = Kc[4] * sy;            // fy*sy
    Kn[6]  = Kc[5] * sy - 1.0f;     // cy*sy-1
    Kn[10] = 1.0f; Kn[15] = 1.0f;
    float P[16];
#pragma unroll
    for (int i = 0; i < 4; i++)
#pragma unroll
        for (int j = 0; j < 4; j++) {
            float s = 0.0f;
#pragma unroll
            for (int k = 0; k < 4; k++) s += Kn[i*4+k] * E[k*4+j];
            P[i*4+j] = s;
        }
    // Gauss-Jordan with partial pivoting
    float M[4][8];
    for (int i = 0; i < 4; i++)
        for (int j = 0; j < 4; j++) { M[i][j] = P[i*4+j]; M[i][4+j] = (i==j) ? 1.0f : 0.0f; }
    for (int col = 0; col < 4; col++) {
        int piv = col;
        for (int r = col+1; r < 4; r++)
            if (fabsf(M[r][col]) > fabsf(M[piv][col])) piv = r;
        if (piv != col)
            for (int j = 0; j < 8; j++) { float tmp = M[col][j]; M[col][j] = M[piv][j]; M[piv][j] = tmp; }
        float d = 1.0f / M[col][col];
        for (int j = 0; j < 8; j++) M[col][j] *= d;
        for (int r = 0; r < 4; r++) {
            if (r == col) continue;
            float f = M[r][col];
            for (int j = 0; j < 8; j++) M[r][j] -= f * M[col][j];
        }
    }
    float Pi[16];
    for (int i = 0; i < 4; i++)
        for (int j = 0; j < 4; j++) Pi[i*4+j] = M[i][4+j];
    float* o = mats + c * 48;
    for (int i = 0; i < 4; i++)
        for (int j = 0; j < 4; j++) o[i*4+j] = Pi[j*4+i];   // Aq = Pinv^T
    for (int t = 0; t < 16; t++) o[16+t] = P[t];            // Ak
    for (int t = 0; t < 16; t++) o[32+t] = Pi[t];           // Ao
}

// ---------------- tiled fp32 GEMM: C[M][Nn] = A[M][K] * B[Nn][K]^T (+bias) ----------------
__global__ __launch_bounds__(256) void gemm_nt(const float* __restrict__ A,
                                               const float* __restrict__ Bw,
                                               const float* __restrict__ bias,
                                               float* __restrict__ C,
                                               int M, int Nn, int Kd) {
    __shared__ __align__(16) float As[16][68];  // [kk][row], pad 68 keeps rows 16B-aligned
    __shared__ __align__(16) float Bs[16][68];
    const int tid = threadIdx.x;
    const int tx = tid & 15, ty = tid >> 4;
    const int row0 = blockIdx.y * 64, col0 = blockIdx.x * 64;
    const int lr = tid >> 2;          // 0..63
    const int lk = (tid & 3) << 2;    // 0,4,8,12
    const float* Ap = A  + (size_t)(row0 + lr) * Kd + lk;
    const float* Bp = Bw + (size_t)(col0 + lr) * Kd + lk;
    float acc[4][4];
#pragma unroll
    for (int i = 0; i < 4; i++)
#pragma unroll
        for (int j = 0; j < 4; j++) acc[i][j] = 0.0f;

    for (int k0 = 0; k0 < Kd; k0 += 16) {
        float4 av = *(const float4*)(Ap + k0);
        float4 bv = *(const float4*)(Bp + k0);
        __syncthreads();
        As[lk+0][lr] = av.x; As[lk+1][lr] = av.y; As[lk+2][lr] = av.z; As[lk+3][lr] = av.w;
        Bs[lk+0][lr] = bv.x; Bs[lk+1][lr] = bv.y; Bs[lk+2][lr] = bv.z; Bs[lk+3][lr] = bv.w;
        __syncthreads();
#pragma unroll
        for (int kk = 0; kk < 16; kk++) {
            float4 a = *(const float4*)&As[kk][ty << 2];
            float4 b = *(const float4*)&Bs[kk][tx << 2];
            float ar[4] = {a.x, a.y, a.z, a.w};
            float br[4] = {b.x, b.y, b.z, b.w};
#pragma unroll
            for (int i = 0; i < 4; i++)
#pragma unroll
                for (int j = 0; j < 4; j++) acc[i][j] += ar[i] * br[j];
        }
    }
    const int col = col0 + (tx << 2);
    float bb[4] = {0.f, 0.f, 0.f, 0.f};
    if (bias) { bb[0] = bias[col]; bb[1] = bias[col+1]; bb[2] = bias[col+2]; bb[3] = bias[col+3]; }
#pragma unroll
    for (int i = 0; i < 4; i++) {
        float4 o;
        o.x = acc[i][0] + bb[0]; o.y = acc[i][1] + bb[1];
        o.z = acc[i][2] + bb[2]; o.w = acc[i][3] + bb[3];
        *(float4*)&C[(size_t)(row0 + (ty << 2) + i) * Nn + col] = o;
    }
}

// ---------------- PRoPE transform on q/k/v ----------------
// wave per (n, h, s); lane = output dim
__global__ __launch_bounds__(256) void transform_qkv(const float* __restrict__ qkv,
                                                     const float* __restrict__ mats,
                                                     float* __restrict__ Qh,
                                                     float* __restrict__ Kh,
                                                     float* __restrict__ Vh) {
    const int wid  = blockIdx.x * 4 + (threadIdx.x >> 6);
    const int lane = threadIdx.x & 63;
    const int s  = wid % 3;
    const int q  = wid / 3;
    const int hh = q & (HEADS - 1);
    const int n  = q >> 4;
    float t = qkv[(size_t)n * (3*DIM) + s * DIM + hh * HD + lane];
    // full-wave shuffles (no divergence around them)
    const int g = lane & ~3;
    float t0 = __shfl(t, g | 0, 64);
    float t1 = __shfl(t, g | 1, 64);
    float t2 = __shfl(t, g | 2, 64);
    float t3 = __shfl(t, g | 3, 64);
    float other = __shfl_xor(t, 1, 64);
    const int cam = n >> 10;
    const float* A = mats + cam * 48 + (s == 0 ? 0 : 16);
    float res;
    if (lane < DPROJ) {
        const int i = lane & 3;
        res = A[i*4+0]*t0 + A[i*4+1]*t1 + A[i*4+2]*t2 + A[i*4+3]*t3;
    } else {
        const int p = n & (NPER - 1);
        const float px = (float)(p & 31), py = (float)(p >> 5);
        const int pt = (lane - DPROJ) >> 1;
        const float fr = powf(100.0f, -(float)(pt & 7) * (1.0f / 8.0f));
        const float ang = (pt < NF ? px : py) * fr;
        const float c = cosf(ang), sn = sinf(ang);
        const float sgn = (lane & 1) ? sn : -sn;   // sign=+1: a'=a c - b s ; b'= a s + b c
        res = t * c + other * sgn;
    }
    float* dst = (s == 0) ? Qh : ((s == 1) ? Kh : Vh);
    dst[(size_t)(hh * N_TOK + n) * HD + lane] = res;
}

// ---------------- inverse transform on attention output, write token-major ----------------
__global__ __launch_bounds__(256) void transform_out(const float* __restrict__ Oh,
                                                     const float* __restrict__ mats,
                                                     float* __restrict__ Ot) {
    const int wid  = blockIdx.x * 4 + (threadIdx.x >> 6);
    const int lane = threadIdx.x & 63;
    const int hh = wid & (HEADS - 1);
    const int n  = wid >> 4;
    float t = Oh[(size_t)(hh * N_TOK + n) * HD + lane];
    const int g = lane & ~3;
    float t0 = __shfl(t, g | 0, 64);
    float t1 = __shfl(t, g | 1, 64);
    float t2 = __shfl(t, g | 2, 64);
    float t3 = __shfl(t, g | 3, 64);
    float other = __shfl_xor(t, 1, 64);
    const int cam = n >> 10;
    const float* A = mats + cam * 48 + 32;   // Ao = Pinv
    float res;
    if (lane < DPROJ) {
        const int i = lane & 3;
        res = A[i*4+0]*t0 + A[i*4+1]*t1 + A[i*4+2]*t2 + A[i*4+3]*t3;
    } else {
        const int p = n & (NPER - 1);
        const float px = (float)(p & 31), py = (float)(p >> 5);
        const int pt = (lane - DPROJ) >> 1;
        const float fr = powf(100.0f, -(float)(pt & 7) * (1.0f / 8.0f));
        const float ang = (pt < NF ? px : py) * fr;
        const float c = cosf(ang), sn = sinf(ang);
        const float sgn = (lane & 1) ? -sn : sn;   // sign=-1
        res = t * c + other * sgn;
    }
    Ot[(size_t)n * DIM + hh * HD + lane] = res;
}

// ---------------- attention: wave handles 4 queries, two-pass softmax ----------------
__global__ __launch_bounds__(256) void attn_kernel(const float* __restrict__ Q,
                                                   const float* __restrict__ K,
                                                   const float* __restrict__ V,
                                                   float* __restrict__ O) {
    __shared__ __align__(16) float qs[4][4][64];    // [wave][qq][d]
    __shared__ __align__(16) float ps[4][4][512];   // [wave][qq][key-in-chunk]
    const int w    = threadIdx.x >> 6;
    const int lane = threadIdx.x & 63;
    const int gid  = blockIdx.x * 4 + w;
    const int hh = gid >> 9;            // 512 query-groups per head
    const int q0 = (gid & 511) << 2;
    const float* Kb = K + (size_t)hh * N_TOK * HD;
    const float* Vb = V + (size_t)hh * N_TOK * HD;

#pragma unroll
    for (int qq = 0; qq < 4; qq++)
        qs[w][qq][lane] = Q[(size_t)(hh * N_TOK + q0 + qq) * HD + lane] * 0.125f; // fold scale
    __syncthreads();

    // ---- pass 1: row max + sumexp (online, per-lane over its 32 keys) ----
    float m[4] = {-1e30f, -1e30f, -1e30f, -1e30f};
    float l[4] = {0.f, 0.f, 0.f, 0.f};
    for (int g = 0; g < 4; g++) {               // 4 groups of 8 keys per lane
        float s[8][4];
#pragma unroll
        for (int e = 0; e < 8; e++)
#pragma unroll
            for (int qq = 0; qq < 4; qq++) s[e][qq] = 0.0f;
#pragma unroll
        for (int t = 0; t < 16; t++) {
            float4 qv[4];
#pragma unroll
            for (int qq = 0; qq < 4; qq++) qv[qq] = *(const float4*)&qs[w][qq][t * 4];
#pragma unroll
            for (int e = 0; e < 8; e++) {
                const int key = (g * 8 + e) * 64 + lane;
                float4 kv = *(const float4*)&Kb[(size_t)key * HD + t * 4];
#pragma unroll
                for (int qq = 0; qq < 4; qq++)
                    s[e][qq] += qv[qq].x*kv.x + qv[qq].y*kv.y + qv[qq].z*kv.z + qv[qq].w*kv.w;
            }
        }
#pragma unroll
        for (int e = 0; e < 8; e++)
#pragma unroll
            for (int qq = 0; qq < 4; qq++) {
                float sc = s[e][qq];
                float mn = fmaxf(m[qq], sc);
                l[qq] = l[qq] * __expf(m[qq] - mn) + __expf(sc - mn);
                m[qq] = mn;
            }
    }
    // cross-lane (m,l) combine
#pragma unroll
    for (int off = 32; off; off >>= 1) {
#pragma unroll
        for (int qq = 0; qq < 4; qq++) {
            float mo = __shfl_xor(m[qq], off, 64);
            float lo = __shfl_xor(l[qq], off, 64);
            float mn = fmaxf(m[qq], mo);
            l[qq] = l[qq] * __expf(m[qq] - mn) + lo * __expf(mo - mn);
            m[qq] = mn;
        }
    }
    float rl[4];
#pragma unroll
    for (int qq = 0; qq < 4; qq++) rl[qq] = 1.0f / l[qq];

    // ---- pass 2: recompute scores per 512-key chunk, accumulate O ----
    float acc[4] = {0.f, 0.f, 0.f, 0.f};
    for (int C0 = 0; C0 < N_TOK; C0 += 512) {
        float s[8][4];
#pragma unroll
        for (int e = 0; e < 8; e++)
#pragma unroll
            for (int qq = 0; qq < 4; qq++) s[e][qq] = 0.0f;
#pragma unroll
        for (int t = 0; t < 16; t++) {
            float4 qv[4];
#pragma unroll
            for (int qq = 0; qq < 4; qq++) qv[qq] = *(const float4*)&qs[w][qq][t * 4];
#pragma unroll
            for (int e = 0; e < 8; e++) {
                const int key = C0 + e * 64 + lane;
                float4 kv = *(const float4*)&Kb[(size_t)key * HD + t * 4];
#pragma unroll
                for (int qq = 0; qq < 4; qq++)
                    s[e][qq] += qv[qq].x*kv.x + qv[qq].y*kv.y + qv[qq].z*kv.z + qv[qq].w*kv.w;
            }
        }
        __syncthreads();
#pragma unroll
        for (int e = 0; e < 8; e++)
#pragma unroll
            for (int qq = 0; qq < 4; qq++)
                ps[w][qq][e * 64 + lane] = __expf(s[e][qq] - m[qq]) * rl[qq];
        __syncthreads();
        const float* Vc = Vb + (size_t)C0 * HD;
        for (int jg = 0; jg < 128; jg++) {
            float4 p0 = *(const float4*)&ps[w][0][jg * 4];
            float4 p1 = *(const float4*)&ps[w][1][jg * 4];
            float4 p2 = *(const float4*)&ps[w][2][jg * 4];
            float4 p3 = *(const float4*)&ps[w][3][jg * 4];
            const float* vr = Vc + (size_t)(jg * 4) * HD + lane;
            float v0 = vr[0*HD], v1 = vr[1*HD], v2 = vr[2*HD], v3 = vr[3*HD];
            acc[0] += p0.x*v0 + p0.y*v1 + p0.z*v2 + p0.w*v3;
            acc[1] += p1.x*v0 + p1.y*v1 + p1.z*v2 + p1.w*v3;
            acc[2] += p2.x*v0 + p2.y*v1 + p2.z*v2 + p2.w*v3;
            acc[3] += p3.x*v0 + p3.y*v1 + p3.z*v2 + p3.w*v3;
        }
        __syncthreads();
    }
#pragma unroll
    for (int qq = 0; qq < 4; qq++)
        O[(size_t)(hh * N_TOK + q0 + qq) * HD + lane] = acc[qq];
}

// ---------------- launcher ----------------
extern "C" void kernel_launch(void* const* d_in, const int* in_sizes, int n_in,
                              void* d_out, int out_size, void* d_ws, size_t ws_size,
                              hipStream_t stream) {
    const float* x      = (const float*)d_in[0];
    const float* ext    = (const float*)d_in[1];
    const float* Ks     = (const float*)d_in[2];
    const float* qkv_w  = (const float*)d_in[3];
    const float* proj_w = (const float*)d_in[4];
    const float* proj_b = (const float*)d_in[5];
    float* out = (float*)d_out;

    float* ws   = (float*)d_ws;
    float* mats = ws + MATS_OFF;
    float* qkvb = ws + QKV_OFF;
    float* Qh   = ws + Q_OFF;
    float* Kh   = ws + K_OFF;
    float* Vh   = ws + V_OFF;
    float* Oh   = ws + O_OFF;
    float* Ot   = ws + OT_OFF;

    build_mats<<<1, 64, 0, stream>>>(ext, Ks, mats);

    // qkv = x @ qkv_w^T : M=2048, Nn=3072, K=1024
    gemm_nt<<<dim3(3*DIM/64, N_TOK/64), 256, 0, stream>>>(x, qkv_w, nullptr, qkvb,
                                                          N_TOK, 3*DIM, DIM);

    // per-head transform (wave per (n,h,s))
    transform_qkv<<<N_TOK * 3 * HEADS / 4, 256, 0, stream>>>(qkvb, mats, Qh, Kh, Vh);

    // attention (wave per 4 queries)
    attn_kernel<<<HEADS * (N_TOK / 4) / 4, 256, 0, stream>>>(Qh, Kh, Vh, Oh);

    // inverse transform + relayout to token-major
    transform_out<<<N_TOK * HEADS / 4, 256, 0, stream>>>(Oh, mats, Ot);

    // out = Ot @ proj_w^T + proj_b : M=2048, Nn=1024, K=1024
    gemm_nt<<<dim3(DIM/64, N_TOK/64), 256, 0, stream>>>(Ot, proj_w, proj_b, out,
                                                        N_TOK, DIM, DIM);
}

// Round 2
// 491.152 us; speedup vs baseline: 4.3092x; 4.3092x over previous
//
#include <hip/hip_runtime.h>
#include <math.h>

// ---------------- problem constants (fixed by reference file) ----------------
#define N_TOK   2048      // NC * PY * PX
#define DIM     1024
#define HEADS   16
#define HD      64        // head dim
#define NCAMS   2
#define NPER    1024      // tokens per camera (32*32)
#define DPROJ   32        // first half: projective 4x4 groups
#define NF      8         // rope freqs

typedef _Float16 half8  __attribute__((ext_vector_type(8)));
typedef _Float16 half4h __attribute__((ext_vector_type(4)));
typedef _Float16 half2h __attribute__((ext_vector_type(2)));
typedef float    floatx4 __attribute__((ext_vector_type(4)));

// ---------------- workspace layout (float-granular offsets) ----------------
#define MATS_OFF 0
#define QKV_OFF  256                                   // 2048*3072 f32
#define Q_OFF    (QKV_OFF + N_TOK*3*DIM)               // f16 regions (fit in f32-sized slots)
#define K_OFF    (Q_OFF + HEADS*N_TOK*HD)
#define V_OFF    (K_OFF + HEADS*N_TOK*HD)
#define O_OFF    (V_OFF + HEADS*N_TOK*HD)              // f32
#define OT_OFF   (O_OFF + HEADS*N_TOK*HD)              // f32

// ---------------- per-camera matrices ----------------
__global__ void build_mats(const float* __restrict__ ext, const float* __restrict__ Ks,
                           float* __restrict__ mats) {
    int c = threadIdx.x;
    if (c >= NCAMS) return;
    const float sx = 2.0f / 448.0f, sy = 2.0f / 448.0f;
    const float* Kc = Ks + c * 9;
    const float* E  = ext + c * 16;
    float Kn[16];
#pragma unroll
    for (int i = 0; i < 16; i++) Kn[i] = 0.0f;
    Kn[0]  = Kc[0] * sx;
    Kn[2]  = Kc[2] * sx - 1.0f;
    Kn[5]  = Kc[4] * sy;
    Kn[6]  = Kc[5] * sy - 1.0f;
    Kn[10] = 1.0f; Kn[15] = 1.0f;
    float P[16];
#pragma unroll
    for (int i = 0; i < 4; i++)
#pragma unroll
        for (int j = 0; j < 4; j++) {
            float s = 0.0f;
#pragma unroll
            for (int k = 0; k < 4; k++) s += Kn[i*4+k] * E[k*4+j];
            P[i*4+j] = s;
        }
    float M[4][8];
    for (int i = 0; i < 4; i++)
        for (int j = 0; j < 4; j++) { M[i][j] = P[i*4+j]; M[i][4+j] = (i==j) ? 1.0f : 0.0f; }
    for (int col = 0; col < 4; col++) {
        int piv = col;
        for (int r = col+1; r < 4; r++)
            if (fabsf(M[r][col]) > fabsf(M[piv][col])) piv = r;
        if (piv != col)
            for (int j = 0; j < 8; j++) { float tmp = M[col][j]; M[col][j] = M[piv][j]; M[piv][j] = tmp; }
        float d = 1.0f / M[col][col];
        for (int j = 0; j < 8; j++) M[col][j] *= d;
        for (int r = 0; r < 4; r++) {
            if (r == col) continue;
            float f = M[r][col];
            for (int j = 0; j < 8; j++) M[r][j] -= f * M[col][j];
        }
    }
    float Pi[16];
    for (int i = 0; i < 4; i++)
        for (int j = 0; j < 4; j++) Pi[i*4+j] = M[i][4+j];
    float* o = mats + c * 48;
    for (int i = 0; i < 4; i++)
        for (int j = 0; j < 4; j++) o[i*4+j] = Pi[j*4+i];   // Aq = Pinv^T
    for (int t = 0; t < 16; t++) o[16+t] = P[t];            // Ak = P
    for (int t = 0; t < 16; t++) o[32+t] = Pi[t];           // Ao = Pinv
}

// ---------------- tiled fp32 GEMM: C[M][Nn] = A[M][K] * B[Nn][K]^T (+bias) ----------------
__global__ __launch_bounds__(256) void gemm_nt(const float* __restrict__ A,
                                               const float* __restrict__ Bw,
                                               const float* __restrict__ bias,
                                               float* __restrict__ C,
                                               int M, int Nn, int Kd) {
    __shared__ __align__(16) float As[16][68];
    __shared__ __align__(16) float Bs[16][68];
    const int tid = threadIdx.x;
    const int tx = tid & 15, ty = tid >> 4;
    const int row0 = blockIdx.y * 64, col0 = blockIdx.x * 64;
    const int lr = tid >> 2;
    const int lk = (tid & 3) << 2;
    const float* Ap = A  + (size_t)(row0 + lr) * Kd + lk;
    const float* Bp = Bw + (size_t)(col0 + lr) * Kd + lk;
    float acc[4][4];
#pragma unroll
    for (int i = 0; i < 4; i++)
#pragma unroll
        for (int j = 0; j < 4; j++) acc[i][j] = 0.0f;

    for (int k0 = 0; k0 < Kd; k0 += 16) {
        float4 av = *(const float4*)(Ap + k0);
        float4 bv = *(const float4*)(Bp + k0);
        __syncthreads();
        As[lk+0][lr] = av.x; As[lk+1][lr] = av.y; As[lk+2][lr] = av.z; As[lk+3][lr] = av.w;
        Bs[lk+0][lr] = bv.x; Bs[lk+1][lr] = bv.y; Bs[lk+2][lr] = bv.z; Bs[lk+3][lr] = bv.w;
        __syncthreads();
#pragma unroll
        for (int kk = 0; kk < 16; kk++) {
            float4 a = *(const float4*)&As[kk][ty << 2];
            float4 b = *(const float4*)&Bs[kk][tx << 2];
            float ar[4] = {a.x, a.y, a.z, a.w};
            float br[4] = {b.x, b.y, b.z, b.w};
#pragma unroll
            for (int i = 0; i < 4; i++)
#pragma unroll
                for (int j = 0; j < 4; j++) acc[i][j] += ar[i] * br[j];
        }
    }
    const int col = col0 + (tx << 2);
    float bb[4] = {0.f, 0.f, 0.f, 0.f};
    if (bias) { bb[0] = bias[col]; bb[1] = bias[col+1]; bb[2] = bias[col+2]; bb[3] = bias[col+3]; }
#pragma unroll
    for (int i = 0; i < 4; i++) {
        float4 o;
        o.x = acc[i][0] + bb[0]; o.y = acc[i][1] + bb[1];
        o.z = acc[i][2] + bb[2]; o.w = acc[i][3] + bb[3];
        *(float4*)&C[(size_t)(row0 + (ty << 2) + i) * Nn + col] = o;
    }
}

// ---------------- PRoPE transform on q/k/v -> f16, V transposed, scale folded into Q ----------------
__global__ __launch_bounds__(256) void transform_qkv(const float* __restrict__ qkv,
                                                     const float* __restrict__ mats,
                                                     _Float16* __restrict__ Qf,
                                                     _Float16* __restrict__ Kf,
                                                     _Float16* __restrict__ Vtf) {
    const int wid  = blockIdx.x * 4 + (threadIdx.x >> 6);
    const int lane = threadIdx.x & 63;
    const int s  = wid % 3;
    const int q  = wid / 3;
    const int hh = q & (HEADS - 1);
    const int n  = q >> 4;
    float t = qkv[(size_t)n * (3*DIM) + s * DIM + hh * HD + lane];
    const int g = lane & ~3;
    float t0 = __shfl(t, g | 0, 64);
    float t1 = __shfl(t, g | 1, 64);
    float t2 = __shfl(t, g | 2, 64);
    float t3 = __shfl(t, g | 3, 64);
    float other = __shfl_xor(t, 1, 64);
    const int cam = n >> 10;
    const float* A = mats + cam * 48 + (s == 0 ? 0 : 16);
    float res;
    if (lane < DPROJ) {
        const int i = lane & 3;
        res = A[i*4+0]*t0 + A[i*4+1]*t1 + A[i*4+2]*t2 + A[i*4+3]*t3;
    } else {
        const int p = n & (NPER - 1);
        const float px = (float)(p & 31), py = (float)(p >> 5);
        const int pt = (lane - DPROJ) >> 1;
        const float fr = powf(100.0f, -(float)(pt & 7) * (1.0f / 8.0f));
        const float ang = (pt < NF ? px : py) * fr;
        const float c = cosf(ang), sn = sinf(ang);
        const float sgn = (lane & 1) ? sn : -sn;
        res = t * c + other * sgn;
    }
    if (s == 0)
        Qf[((size_t)hh * N_TOK + n) * HD + lane] = (_Float16)(res * 0.125f); // fold 1/sqrt(64)
    else if (s == 1)
        Kf[((size_t)hh * N_TOK + n) * HD + lane] = (_Float16)res;
    else
        Vtf[((size_t)hh * HD + lane) * N_TOK + n] = (_Float16)res;           // transposed [h][d][n]
}

// ---------------- inverse transform on attention output, write token-major ----------------
__global__ __launch_bounds__(256) void transform_out(const float* __restrict__ Oh,
                                                     const float* __restrict__ mats,
                                                     float* __restrict__ Ot) {
    const int wid  = blockIdx.x * 4 + (threadIdx.x >> 6);
    const int lane = threadIdx.x & 63;
    const int hh = wid & (HEADS - 1);
    const int n  = wid >> 4;
    float t = Oh[(size_t)(hh * N_TOK + n) * HD + lane];
    const int g = lane & ~3;
    float t0 = __shfl(t, g | 0, 64);
    float t1 = __shfl(t, g | 1, 64);
    float t2 = __shfl(t, g | 2, 64);
    float t3 = __shfl(t, g | 3, 64);
    float other = __shfl_xor(t, 1, 64);
    const int cam = n >> 10;
    const float* A = mats + cam * 48 + 32;
    float res;
    if (lane < DPROJ) {
        const int i = lane & 3;
        res = A[i*4+0]*t0 + A[i*4+1]*t1 + A[i*4+2]*t2 + A[i*4+3]*t3;
    } else {
        const int p = n & (NPER - 1);
        const float px = (float)(p & 31), py = (float)(p >> 5);
        const int pt = (lane - DPROJ) >> 1;
        const float fr = powf(100.0f, -(float)(pt & 7) * (1.0f / 8.0f));
        const float ang = (pt < NF ? px : py) * fr;
        const float c = cosf(ang), sn = sinf(ang);
        const float sgn = (lane & 1) ? -sn : sn;
        res = t * c + other * sgn;
    }
    Ot[(size_t)n * DIM + hh * HD + lane] = res;
}

// ---------------- MFMA flash attention ----------------
// Wave = 16 q-rows. Block = 4 waves = 64 q-rows. Grid = 16 heads * 32 = 512.
// S^T = K.Q^T  (D-layout: m=key=quad*4+r, n=q=lane&15)
// O^T = V^T.P  (A = Vt rows from global, B = P via per-wave LDS strip)
#define PLD 68   // LDS leading dim (halves): breaks power-of-2 bank stride
__global__ __launch_bounds__(256) void attn_mfma(const _Float16* __restrict__ Qh,
                                                 const _Float16* __restrict__ Kh,
                                                 const _Float16* __restrict__ Vt,
                                                 float* __restrict__ Oh) {
    __shared__ _Float16 P_lds[4][16][PLD];
    const int w    = threadIdx.x >> 6;
    const int lane = threadIdx.x & 63;
    const int hh = blockIdx.x >> 5;
    const int qb = blockIdx.x & 31;
    const int ql = lane & 15, quad = lane >> 4;
    const int q0 = qb * 64 + w * 16;

    // Q B-fragments: held in registers for the whole kernel
    const _Float16* Qp = Qh + ((size_t)hh * N_TOK + q0 + ql) * HD;
    const half8 qf0 = *(const half8*)(Qp + quad * 8);        // dims 0..31
    const half8 qf1 = *(const half8*)(Qp + 32 + quad * 8);   // dims 32..63

    const _Float16* Kb = Kh + (size_t)hh * N_TOK * HD;
    const _Float16* Vb = Vt + (size_t)hh * HD * N_TOK;

    floatx4 O[4];
#pragma unroll
    for (int mt = 0; mt < 4; mt++) O[mt] = (floatx4){0.f, 0.f, 0.f, 0.f};
    float m = -1e30f, l = 0.0f;

    for (int kb = 0; kb < N_TOK; kb += 64) {
        // ---- S^T = K . Q^T over 64 keys ----
        floatx4 s[4];
#pragma unroll
        for (int kt = 0; kt < 4; kt++) {
            const _Float16* Kp = Kb + (size_t)(kb + kt * 16 + ql) * HD;
            half8 ka0 = *(const half8*)(Kp + quad * 8);
            half8 ka1 = *(const half8*)(Kp + 32 + quad * 8);
            floatx4 acc = (floatx4){0.f, 0.f, 0.f, 0.f};
            acc = __builtin_amdgcn_mfma_f32_16x16x32_f16(ka0, qf0, acc, 0, 0, 0);
            acc = __builtin_amdgcn_mfma_f32_16x16x32_f16(ka1, qf1, acc, 0, 0, 0);
            s[kt] = acc;
        }
        // ---- online softmax (per q = lane&15; reduce across quads) ----
        float bm = -1e30f;
#pragma unroll
        for (int kt = 0; kt < 4; kt++)
#pragma unroll
            for (int r = 0; r < 4; r++) bm = fmaxf(bm, s[kt][r]);
        bm = fmaxf(bm, __shfl_xor(bm, 16, 64));
        bm = fmaxf(bm, __shfl_xor(bm, 32, 64));
        const float mnew = fmaxf(m, bm);
        const float alpha = __expf(m - mnew);
        float p[4][4];
        float ps = 0.0f;
#pragma unroll
        for (int kt = 0; kt < 4; kt++)
#pragma unroll
            for (int r = 0; r < 4; r++) { p[kt][r] = __expf(s[kt][r] - mnew); ps += p[kt][r]; }
        ps += __shfl_xor(ps, 16, 64);
        ps += __shfl_xor(ps, 32, 64);
        l = l * alpha + ps;
        m = mnew;
#pragma unroll
        for (int mt = 0; mt < 4; mt++)
#pragma unroll
            for (int r = 0; r < 4; r++) O[mt][r] *= alpha;
        // ---- P -> per-wave LDS strip (P_lds[q][key]) ----
#pragma unroll
        for (int kt = 0; kt < 4; kt++) {
            half2h p01 = {(_Float16)p[kt][0], (_Float16)p[kt][1]};
            half2h p23 = {(_Float16)p[kt][2], (_Float16)p[kt][3]};
            *(half2h*)&P_lds[w][ql][kt * 16 + quad * 4]     = p01;
            *(half2h*)&P_lds[w][ql][kt * 16 + quad * 4 + 2] = p23;
        }
        // ---- B-frags of P (same-wave LDS; DS ops complete in order per wave) ----
        half4h pa = *(const half4h*)&P_lds[w][ql][quad * 8];
        half4h pb = *(const half4h*)&P_lds[w][ql][quad * 8 + 4];
        half4h pc = *(const half4h*)&P_lds[w][ql][32 + quad * 8];
        half4h pd = *(const half4h*)&P_lds[w][ql][32 + quad * 8 + 4];
        half8 pf0, pf1;
#pragma unroll
        for (int j = 0; j < 4; j++) { pf0[j] = pa[j]; pf0[4 + j] = pb[j]; pf1[j] = pc[j]; pf1[4 + j] = pd[j]; }
        // ---- O^T += V^T . P ----
#pragma unroll
        for (int mt = 0; mt < 4; mt++) {
            const _Float16* Vp = Vb + (size_t)(mt * 16 + ql) * N_TOK + kb;
            half8 va0 = *(const half8*)(Vp + quad * 8);
            half8 va1 = *(const half8*)(Vp + 32 + quad * 8);
            O[mt] = __builtin_amdgcn_mfma_f32_16x16x32_f16(va0, pf0, O[mt], 0, 0, 0);
            O[mt] = __builtin_amdgcn_mfma_f32_16x16x32_f16(va1, pf1, O[mt], 0, 0, 0);
        }
    }
    const float rl = 1.0f / l;
    float* Op = Oh + ((size_t)hh * N_TOK + q0 + ql) * HD;
#pragma unroll
    for (int mt = 0; mt < 4; mt++)
#pragma unroll
        for (int r = 0; r < 4; r++)
            Op[mt * 16 + quad * 4 + r] = O[mt][r] * rl;
}

// ---------------- launcher ----------------
extern "C" void kernel_launch(void* const* d_in, const int* in_sizes, int n_in,
                              void* d_out, int out_size, void* d_ws, size_t ws_size,
                              hipStream_t stream) {
    const float* x      = (const float*)d_in[0];
    const float* ext    = (const float*)d_in[1];
    const float* Ks     = (const float*)d_in[2];
    const float* qkv_w  = (const float*)d_in[3];
    const float* proj_w = (const float*)d_in[4];
    const float* proj_b = (const float*)d_in[5];
    float* out = (float*)d_out;

    float* ws   = (float*)d_ws;
    float* mats = ws + MATS_OFF;
    float* qkvb = ws + QKV_OFF;
    _Float16* Qf  = (_Float16*)(ws + Q_OFF);
    _Float16* Kf  = (_Float16*)(ws + K_OFF);
    _Float16* Vtf = (_Float16*)(ws + V_OFF);
    float* Oh   = ws + O_OFF;
    float* Ot   = ws + OT_OFF;

    build_mats<<<1, 64, 0, stream>>>(ext, Ks, mats);

    gemm_nt<<<dim3(3*DIM/64, N_TOK/64), 256, 0, stream>>>(x, qkv_w, nullptr, qkvb,
                                                          N_TOK, 3*DIM, DIM);

    transform_qkv<<<N_TOK * 3 * HEADS / 4, 256, 0, stream>>>(qkvb, mats, Qf, Kf, Vtf);

    attn_mfma<<<HEADS * (N_TOK / 64), 256, 0, stream>>>(Qf, Kf, Vtf, Oh);

    transform_out<<<N_TOK * HEADS / 4, 256, 0, stream>>>(Oh, mats, Ot);

    gemm_nt<<<dim3(DIM/64, N_TOK/64), 256, 0, stream>>>(Ot, proj_w, proj_b, out,
                                                        N_TOK, DIM, DIM);
}

// Round 3
// 279.579 us; speedup vs baseline: 7.5702x; 1.7568x over previous
//
#include <hip/hip_runtime.h>
#include <math.h>

// ---------------- problem constants (fixed by reference file) ----------------
#define N_TOK   2048      // NC * PY * PX
#define DIM     1024
#define HEADS   16
#define HD      64        // head dim
#define NCAMS   2
#define NPER    1024      // tokens per camera (32*32)
#define DPROJ   32        // first half: projective 4x4 groups
#define NF      8         // rope freqs

typedef _Float16 half8  __attribute__((ext_vector_type(8)));
typedef _Float16 half4h __attribute__((ext_vector_type(4)));
typedef _Float16 half2h __attribute__((ext_vector_type(2)));
typedef float    floatx4 __attribute__((ext_vector_type(4)));

// ---------------- workspace layout (float-granular offsets) ----------------
#define MATS_OFF  0
#define XF_OFF    256                              // x   f16: 2M halves = 1M floats
#define WQKV_OFF  (XF_OFF   + 1024*1024)           // qkv_w f16: 3M halves = 1.5M floats
#define WPROJ_OFF (WQKV_OFF + 1536*1024)           // proj_w f16: 1M halves = 0.5M floats
#define QKV16_OFF (WPROJ_OFF + 512*1024)           // qkv out f16: 6M halves = 3M floats
#define Q_OFF     (QKV16_OFF + 3*1024*1024)        // f16 2M halves = 1M floats each
#define K_OFF     (Q_OFF + 1024*1024)
#define V_OFF     (K_OFF + 1024*1024)
#define O_OFF     (V_OFF + 1024*1024)              // f32 2M floats
#define OT_OFF    (O_OFF + 2*1024*1024)            // f16 2M halves = 1M floats
// total ~= 11.8M floats ~= 47 MB

// ---------------- async global->LDS (16B per lane, wave-uniform LDS base) ----------------
__device__ __forceinline__ void gl_lds16(const void* g, void* s) {
    __builtin_amdgcn_global_load_lds((const __attribute__((address_space(1))) void*)g,
                                     (__attribute__((address_space(3))) void*)s, 16, 0, 0);
}

// ---------------- per-camera matrices ----------------
__global__ void build_mats(const float* __restrict__ ext, const float* __restrict__ Ks,
                           float* __restrict__ mats) {
    int c = threadIdx.x;
    if (c >= NCAMS) return;
    const float sx = 2.0f / 448.0f, sy = 2.0f / 448.0f;
    const float* Kc = Ks + c * 9;
    const float* E  = ext + c * 16;
    float Kn[16];
#pragma unroll
    for (int i = 0; i < 16; i++) Kn[i] = 0.0f;
    Kn[0]  = Kc[0] * sx;
    Kn[2]  = Kc[2] * sx - 1.0f;
    Kn[5]  = Kc[4] * sy;
    Kn[6]  = Kc[5] * sy - 1.0f;
    Kn[10] = 1.0f; Kn[15] = 1.0f;
    float P[16];
#pragma unroll
    for (int i = 0; i < 4; i++)
#pragma unroll
        for (int j = 0; j < 4; j++) {
            float s = 0.0f;
#pragma unroll
            for (int k = 0; k < 4; k++) s += Kn[i*4+k] * E[k*4+j];
            P[i*4+j] = s;
        }
    float M[4][8];
    for (int i = 0; i < 4; i++)
        for (int j = 0; j < 4; j++) { M[i][j] = P[i*4+j]; M[i][4+j] = (i==j) ? 1.0f : 0.0f; }
    for (int col = 0; col < 4; col++) {
        int piv = col;
        for (int r = col+1; r < 4; r++)
            if (fabsf(M[r][col]) > fabsf(M[piv][col])) piv = r;
        if (piv != col)
            for (int j = 0; j < 8; j++) { float tmp = M[col][j]; M[col][j] = M[piv][j]; M[piv][j] = tmp; }
        float d = 1.0f / M[col][col];
        for (int j = 0; j < 8; j++) M[col][j] *= d;
        for (int r = 0; r < 4; r++) {
            if (r == col) continue;
            float f = M[r][col];
            for (int j = 0; j < 8; j++) M[r][j] -= f * M[col][j];
        }
    }
    float Pi[16];
    for (int i = 0; i < 4; i++)
        for (int j = 0; j < 4; j++) Pi[i*4+j] = M[i][4+j];
    float* o = mats + c * 48;
    for (int i = 0; i < 4; i++)
        for (int j = 0; j < 4; j++) o[i*4+j] = Pi[j*4+i];   // Aq = Pinv^T
    for (int t = 0; t < 16; t++) o[16+t] = P[t];            // Ak = P
    for (int t = 0; t < 16; t++) o[32+t] = Pi[t];           // Ao = Pinv
}

// ---------------- cast x / qkv_w / proj_w to f16 (one launch) ----------------
// segments: x 2M | qkv_w 3M | proj_w 1M floats, each a multiple of 8
__global__ __launch_bounds__(256) void cast_inputs(const float* __restrict__ x,
                                                   const float* __restrict__ wqkv,
                                                   const float* __restrict__ wproj,
                                                   _Float16* __restrict__ xf,
                                                   _Float16* __restrict__ wqkvf,
                                                   _Float16* __restrict__ wprojf) {
    size_t i = ((size_t)blockIdx.x * 256 + threadIdx.x) * 8;
    const float* src; _Float16* dst; size_t off;
    if (i < (size_t)2*1024*1024)       { src = x;     dst = xf;     off = i; }
    else if (i < (size_t)5*1024*1024)  { src = wqkv;  dst = wqkvf;  off = i - (size_t)2*1024*1024; }
    else                               { src = wproj; dst = wprojf; off = i - (size_t)5*1024*1024; }
    float4 a = *(const float4*)(src + off);
    float4 b = *(const float4*)(src + off + 4);
    half8 h;
    h[0] = (_Float16)a.x; h[1] = (_Float16)a.y; h[2] = (_Float16)a.z; h[3] = (_Float16)a.w;
    h[4] = (_Float16)b.x; h[5] = (_Float16)b.y; h[6] = (_Float16)b.z; h[7] = (_Float16)b.w;
    *(half8*)(dst + off) = h;
}

// ---------------- MFMA f16 GEMM: C[M][Nn] = A[M][K] . B[Nn][K]^T ----------------
// 128x128 tile, BK=32, 4 waves each computing a 64x64 quadrant (4x4 of 16x16x32).
// Staging via global_load_lds width=16 (m97 structure).
template <bool F16OUT>
__global__ __launch_bounds__(256) void gemm_mfma(const _Float16* __restrict__ A,
                                                 const _Float16* __restrict__ Bw,
                                                 const float* __restrict__ bias,
                                                 void* __restrict__ C,
                                                 int Nn, int Kd) {
    __shared__ _Float16 As[128 * 32];
    __shared__ _Float16 Bs[128 * 32];
    const int tid  = threadIdx.x;
    const int w    = tid >> 6, lane = tid & 63;
    const int ql   = lane & 15, quad = lane >> 4;
    const int lr   = lane >> 2, lc = lane & 3;        // staging: row-in-16, 16B-chunk
    const int wm   = w >> 1, wn = w & 1;
    const int row0 = blockIdx.y * 128, col0 = blockIdx.x * 128;

    floatx4 acc[4][4];
#pragma unroll
    for (int mt = 0; mt < 4; mt++)
#pragma unroll
        for (int nt = 0; nt < 4; nt++) acc[mt][nt] = (floatx4){0.f, 0.f, 0.f, 0.f};

    const _Float16* Ab = A  + (size_t)(row0 + w * 32 + lr) * Kd + lc * 8;
    const _Float16* Bb = Bw + (size_t)(col0 + w * 32 + lr) * Kd + lc * 8;
    _Float16* AsW = &As[(w * 32) * 32];
    _Float16* BsW = &Bs[(w * 32) * 32];

    for (int k0 = 0; k0 < Kd; k0 += 32) {
        gl_lds16(Ab + k0,            AsW);
        gl_lds16(Ab + 16 * Kd + k0,  AsW + 16 * 32);
        gl_lds16(Bb + k0,            BsW);
        gl_lds16(Bb + 16 * Kd + k0,  BsW + 16 * 32);
        __syncthreads();                         // drains vmcnt, loads visible
        half8 af[4], bf[4];
#pragma unroll
        for (int mt = 0; mt < 4; mt++)
            af[mt] = *(const half8*)&As[(wm * 64 + mt * 16 + ql) * 32 + quad * 8];
#pragma unroll
        for (int nt = 0; nt < 4; nt++)
            bf[nt] = *(const half8*)&Bs[(wn * 64 + nt * 16 + ql) * 32 + quad * 8];
#pragma unroll
        for (int mt = 0; mt < 4; mt++)
#pragma unroll
            for (int nt = 0; nt < 4; nt++)
                acc[mt][nt] = __builtin_amdgcn_mfma_f32_16x16x32_f16(af[mt], bf[nt], acc[mt][nt], 0, 0, 0);
        __syncthreads();                         // all reads done before next stage
    }

#pragma unroll
    for (int nt = 0; nt < 4; nt++) {
        const int col = col0 + wn * 64 + nt * 16 + ql;
        float bb = F16OUT ? 0.0f : bias[col];
#pragma unroll
        for (int mt = 0; mt < 4; mt++) {
            const int row = row0 + wm * 64 + mt * 16 + quad * 4;
            if (F16OUT) {
                _Float16* Cp = (_Float16*)C;
#pragma unroll
                for (int r = 0; r < 4; r++)
                    Cp[(size_t)(row + r) * Nn + col] = (_Float16)acc[mt][nt][r];
            } else {
                float* Cp = (float*)C;
#pragma unroll
                for (int r = 0; r < 4; r++)
                    Cp[(size_t)(row + r) * Nn + col] = acc[mt][nt][r] + bb;
            }
        }
    }
}

// ---------------- PRoPE transform on q/k/v -> f16, V transposed, scale folded into Q ----------------
__global__ __launch_bounds__(256) void transform_qkv(const _Float16* __restrict__ qkv,
                                                     const float* __restrict__ mats,
                                                     _Float16* __restrict__ Qf,
                                                     _Float16* __restrict__ Kf,
                                                     _Float16* __restrict__ Vtf) {
    const int wid  = blockIdx.x * 4 + (threadIdx.x >> 6);
    const int lane = threadIdx.x & 63;
    const int s  = wid % 3;
    const int q  = wid / 3;
    const int hh = q & (HEADS - 1);
    const int n  = q >> 4;
    float t = (float)qkv[(size_t)n * (3*DIM) + s * DIM + hh * HD + lane];
    const int g = lane & ~3;
    float t0 = __shfl(t, g | 0, 64);
    float t1 = __shfl(t, g | 1, 64);
    float t2 = __shfl(t, g | 2, 64);
    float t3 = __shfl(t, g | 3, 64);
    float other = __shfl_xor(t, 1, 64);
    const int cam = n >> 10;
    const float* A = mats + cam * 48 + (s == 0 ? 0 : 16);
    float res;
    if (lane < DPROJ) {
        const int i = lane & 3;
        res = A[i*4+0]*t0 + A[i*4+1]*t1 + A[i*4+2]*t2 + A[i*4+3]*t3;
    } else {
        const int p = n & (NPER - 1);
        const float px = (float)(p & 31), py = (float)(p >> 5);
        const int pt = (lane - DPROJ) >> 1;
        const float fr = __expf(-0.5756462732485114f * (float)(pt & 7)); // 100^(-j/8)
        const float ang = (pt < NF ? px : py) * fr;
        float sn, c;
        __sincosf(ang, &sn, &c);
        const float sgn = (lane & 1) ? sn : -sn;
        res = t * c + other * sgn;
    }
    if (s == 0)
        Qf[((size_t)hh * N_TOK + n) * HD + lane] = (_Float16)(res * 0.125f); // fold 1/sqrt(64)
    else if (s == 1)
        Kf[((size_t)hh * N_TOK + n) * HD + lane] = (_Float16)res;
    else
        Vtf[((size_t)hh * HD + lane) * N_TOK + n] = (_Float16)res;           // [h][d][n]
}

// ---------------- inverse transform on attention output -> f16 token-major ----------------
__global__ __launch_bounds__(256) void transform_out(const float* __restrict__ Oh,
                                                     const float* __restrict__ mats,
                                                     _Float16* __restrict__ Ot) {
    const int wid  = blockIdx.x * 4 + (threadIdx.x >> 6);
    const int lane = threadIdx.x & 63;
    const int hh = wid & (HEADS - 1);
    const int n  = wid >> 4;
    float t = Oh[(size_t)(hh * N_TOK + n) * HD + lane];
    const int g = lane & ~3;
    float t0 = __shfl(t, g | 0, 64);
    float t1 = __shfl(t, g | 1, 64);
    float t2 = __shfl(t, g | 2, 64);
    float t3 = __shfl(t, g | 3, 64);
    float other = __shfl_xor(t, 1, 64);
    const int cam = n >> 10;
    const float* A = mats + cam * 48 + 32;
    float res;
    if (lane < DPROJ) {
        const int i = lane & 3;
        res = A[i*4+0]*t0 + A[i*4+1]*t1 + A[i*4+2]*t2 + A[i*4+3]*t3;
    } else {
        const int p = n & (NPER - 1);
        const float px = (float)(p & 31), py = (float)(p >> 5);
        const int pt = (lane - DPROJ) >> 1;
        const float fr = __expf(-0.5756462732485114f * (float)(pt & 7));
        const float ang = (pt < NF ? px : py) * fr;
        float sn, c;
        __sincosf(ang, &sn, &c);
        const float sgn = (lane & 1) ? -sn : sn;   // sign=-1
        res = t * c + other * sgn;
    }
    Ot[(size_t)n * DIM + hh * HD + lane] = (_Float16)res;
}

// ---------------- MFMA flash attention (unchanged from round 2) ----------------
#define PLD 68
__global__ __launch_bounds__(256) void attn_mfma(const _Float16* __restrict__ Qh,
                                                 const _Float16* __restrict__ Kh,
                                                 const _Float16* __restrict__ Vt,
                                                 float* __restrict__ Oh) {
    __shared__ _Float16 P_lds[4][16][PLD];
    const int w    = threadIdx.x >> 6;
    const int lane = threadIdx.x & 63;
    const int hh = blockIdx.x >> 5;
    const int qb = blockIdx.x & 31;
    const int ql = lane & 15, quad = lane >> 4;
    const int q0 = qb * 64 + w * 16;

    const _Float16* Qp = Qh + ((size_t)hh * N_TOK + q0 + ql) * HD;
    const half8 qf0 = *(const half8*)(Qp + quad * 8);
    const half8 qf1 = *(const half8*)(Qp + 32 + quad * 8);

    const _Float16* Kb = Kh + (size_t)hh * N_TOK * HD;
    const _Float16* Vb = Vt + (size_t)hh * HD * N_TOK;

    floatx4 O[4];
#pragma unroll
    for (int mt = 0; mt < 4; mt++) O[mt] = (floatx4){0.f, 0.f, 0.f, 0.f};
    float m = -1e30f, l = 0.0f;

    for (int kb = 0; kb < N_TOK; kb += 64) {
        floatx4 s[4];
#pragma unroll
        for (int kt = 0; kt < 4; kt++) {
            const _Float16* Kp = Kb + (size_t)(kb + kt * 16 + ql) * HD;
            half8 ka0 = *(const half8*)(Kp + quad * 8);
            half8 ka1 = *(const half8*)(Kp + 32 + quad * 8);
            floatx4 acc = (floatx4){0.f, 0.f, 0.f, 0.f};
            acc = __builtin_amdgcn_mfma_f32_16x16x32_f16(ka0, qf0, acc, 0, 0, 0);
            acc = __builtin_amdgcn_mfma_f32_16x16x32_f16(ka1, qf1, acc, 0, 0, 0);
            s[kt] = acc;
        }
        float bm = -1e30f;
#pragma unroll
        for (int kt = 0; kt < 4; kt++)
#pragma unroll
            for (int r = 0; r < 4; r++) bm = fmaxf(bm, s[kt][r]);
        bm = fmaxf(bm, __shfl_xor(bm, 16, 64));
        bm = fmaxf(bm, __shfl_xor(bm, 32, 64));
        const float mnew = fmaxf(m, bm);
        const float alpha = __expf(m - mnew);
        float p[4][4];
        float ps = 0.0f;
#pragma unroll
        for (int kt = 0; kt < 4; kt++)
#pragma unroll
            for (int r = 0; r < 4; r++) { p[kt][r] = __expf(s[kt][r] - mnew); ps += p[kt][r]; }
        ps += __shfl_xor(ps, 16, 64);
        ps += __shfl_xor(ps, 32, 64);
        l = l * alpha + ps;
        m = mnew;
#pragma unroll
        for (int mt = 0; mt < 4; mt++)
#pragma unroll
            for (int r = 0; r < 4; r++) O[mt][r] *= alpha;
#pragma unroll
        for (int kt = 0; kt < 4; kt++) {
            half2h p01 = {(_Float16)p[kt][0], (_Float16)p[kt][1]};
            half2h p23 = {(_Float16)p[kt][2], (_Float16)p[kt][3]};
            *(half2h*)&P_lds[w][ql][kt * 16 + quad * 4]     = p01;
            *(half2h*)&P_lds[w][ql][kt * 16 + quad * 4 + 2] = p23;
        }
        half4h pa = *(const half4h*)&P_lds[w][ql][quad * 8];
        half4h pb = *(const half4h*)&P_lds[w][ql][quad * 8 + 4];
        half4h pc = *(const half4h*)&P_lds[w][ql][32 + quad * 8];
        half4h pd = *(const half4h*)&P_lds[w][ql][32 + quad * 8 + 4];
        half8 pf0, pf1;
#pragma unroll
        for (int j = 0; j < 4; j++) { pf0[j] = pa[j]; pf0[4 + j] = pb[j]; pf1[j] = pc[j]; pf1[4 + j] = pd[j]; }
#pragma unroll
        for (int mt = 0; mt < 4; mt++) {
            const _Float16* Vp = Vb + (size_t)(mt * 16 + ql) * N_TOK + kb;
            half8 va0 = *(const half8*)(Vp + quad * 8);
            half8 va1 = *(const half8*)(Vp + 32 + quad * 8);
            O[mt] = __builtin_amdgcn_mfma_f32_16x16x32_f16(va0, pf0, O[mt], 0, 0, 0);
            O[mt] = __builtin_amdgcn_mfma_f32_16x16x32_f16(va1, pf1, O[mt], 0, 0, 0);
        }
    }
    const float rl = 1.0f / l;
    float* Op = Oh + ((size_t)hh * N_TOK + q0 + ql) * HD;
#pragma unroll
    for (int mt = 0; mt < 4; mt++)
#pragma unroll
        for (int r = 0; r < 4; r++)
            Op[mt * 16 + quad * 4 + r] = O[mt][r] * rl;
}

// ---------------- launcher ----------------
extern "C" void kernel_launch(void* const* d_in, const int* in_sizes, int n_in,
                              void* d_out, int out_size, void* d_ws, size_t ws_size,
                              hipStream_t stream) {
    const float* x      = (const float*)d_in[0];
    const float* ext    = (const float*)d_in[1];
    const float* Ks     = (const float*)d_in[2];
    const float* qkv_w  = (const float*)d_in[3];
    const float* proj_w = (const float*)d_in[4];
    const float* proj_b = (const float*)d_in[5];
    float* out = (float*)d_out;

    float* ws   = (float*)d_ws;
    float* mats = ws + MATS_OFF;
    _Float16* Xf     = (_Float16*)(ws + XF_OFF);
    _Float16* Wqkvf  = (_Float16*)(ws + WQKV_OFF);
    _Float16* Wprojf = (_Float16*)(ws + WPROJ_OFF);
    _Float16* qkv16  = (_Float16*)(ws + QKV16_OFF);
    _Float16* Qf  = (_Float16*)(ws + Q_OFF);
    _Float16* Kf  = (_Float16*)(ws + K_OFF);
    _Float16* Vtf = (_Float16*)(ws + V_OFF);
    float* Oh   = ws + O_OFF;
    _Float16* Ot16 = (_Float16*)(ws + OT_OFF);

    build_mats<<<1, 64, 0, stream>>>(ext, Ks, mats);

    cast_inputs<<<3072, 256, 0, stream>>>(x, qkv_w, proj_w, Xf, Wqkvf, Wprojf);

    // qkv16 = x @ qkv_w^T : M=2048, Nn=3072, K=1024
    gemm_mfma<true><<<dim3(3*DIM/128, N_TOK/128), 256, 0, stream>>>(
        Xf, Wqkvf, nullptr, (void*)qkv16, 3*DIM, DIM);

    transform_qkv<<<N_TOK * 3 * HEADS / 4, 256, 0, stream>>>(qkv16, mats, Qf, Kf, Vtf);

    attn_mfma<<<HEADS * (N_TOK / 64), 256, 0, stream>>>(Qf, Kf, Vtf, Oh);

    transform_out<<<N_TOK * HEADS / 4, 256, 0, stream>>>(Oh, mats, Ot16);

    // out = Ot @ proj_w^T + proj_b : M=2048, Nn=1024, K=1024
    gemm_mfma<false><<<dim3(DIM/128, N_TOK/128), 256, 0, stream>>>(
        Ot16, Wprojf, proj_b, (void*)out, DIM, DIM);
}